// Round 5
// baseline (69.812 us; speedup 1.0000x reference)
//
#include <hip/hip_runtime.h>
#include <math.h>

// KDE log-density: out[i] = log(1e-8 + (1/N) * sum_j exp(t1 - 50*||xe_i - xb_j||^2))
// N = 16384, D = 16, fp32 in/out.
//
// Round 10: fused conversion + lean LDS loop.
//  - Round-9 post-mortem: LDS-fed B confirmed the L1-BW theory (68.4->66.6).
//    kde_main ~4.5 us vs ~2.5-3 us VALU floor (8 v_max3 + cmp per tile);
//    slack = loop/pointer overhead + the now-pointless prefetch-1 structure.
//    kde_pre (+launch gap, +3MB xe16/xb16/pe/pbthr roundtrip) is overhead
//    now that main stages through LDS anyway.
//  - Fix 1: convert INSIDE kde_main. Block stages raw fp32 xb j-slice ->
//    scaled bf16 + thr directly in LDS; waves convert own A rows and build
//    pe cooperatively (exact kde_pre fp32 summation order, LDS exchange).
//    kde_pre shrinks to S=0 / out=log(1e-8) init (16 blocks).
//  - Fix 2: flat #pragma unroll 8 loop, every ds_read = base + immediate
//    offset, no manual prefetch/peel.
//  - Screen and rare exp/atomicAdd/atomicMin path: VERBATIM round 5.
//    All conversions bit-identical (same f32_to_bf16_rne, same fp32 order).

#define KDE_N 16384
#define KDE_D 16
#define MT 32                  // rows per wave m-tile
#define MWAVES 8               // waves per block
#define MB (MT * MWAVES)       // 256 eval rows per block
#define JSPLIT 16
#define JTILES (KDE_N / 32 / JSPLIT)   // 32 j-tiles per wave
#define THR (-135.0f)          // log2-domain underflow screen
#define LOG1EM8 -18.420680743952367f   // log(1e-8)

typedef __attribute__((ext_vector_type(8)))  short   short8;
typedef __attribute__((ext_vector_type(16))) float   float16_t;

__device__ __forceinline__ unsigned short f32_to_bf16_rne(float f) {
    unsigned int u = __float_as_uint(f);
    unsigned int r = (u + 0x7FFFu + ((u >> 16) & 1u)) >> 16;
    return (unsigned short)r;
}

__device__ __forceinline__ unsigned int pack2_scaled(float a, float b) {
    const float SQSC = 12.011224664550577f;   // sqrt(100*log2e)
    return (unsigned int)f32_to_bf16_rne(a * SQSC)
         | ((unsigned int)f32_to_bf16_rne(b * SQSC) << 16);
}

// ---- tiny init: S = 0, out = log(1e-8) ----
__global__ void kde_init(float* __restrict__ S, float* __restrict__ out)
{
    const int i = (blockIdx.x * 256 + threadIdx.x) * 4;
    *(float4*)(S + i)   = make_float4(0.f, 0.f, 0.f, 0.f);
    *(float4*)(out + i) = make_float4(LOG1EM8, LOG1EM8, LOG1EM8, LOG1EM8);
}

// ---- main: fused convert+stage, LDS-fed MFMA + max-screen ----
__global__ __launch_bounds__(512, 8) void kde_main(
    const float* __restrict__ xe, const float* __restrict__ xb,
    float* __restrict__ S, float* __restrict__ out)
{
    // smem: B bf16 [1024 rows x 32 B] = 32768 | thr [1024 f32] = 4096 |
    //       pe exchange [8 waves x 32 f32] = 1024   => 37888 B (x4 blocks <= 160K)
    __shared__ char smem[37888];

    const int tid  = threadIdx.x;
    const int lane = tid & 63;
    const int wave = tid >> 6;                      // 0..7
    const int m0   = blockIdx.y * MB + wave * MT;
    const int jbase = blockIdx.x * 1024;            // global B row base (j fast dim)

    const float T1L2E = -17.8920067984f;            // log2e * t1
    const float C72   = 72.134752044447963f;        // 50 * log2e

    // ---- stage B j-slice: raw fp32 -> scaled bf16 in LDS, + thr ----
    #pragma unroll
    for (int k = 0; k < 2; ++k) {
        const int row = k * 512 + tid;              // 0..1023
        const float4* s4 = (const float4*)(xb + (size_t)(jbase + row) * KDE_D);
        float q = 0.f;
        unsigned int w[8];
        #pragma unroll
        for (int kk = 0; kk < 4; ++kk) {
            float4 v = s4[kk];
            q += v.x*v.x + v.y*v.y + v.z*v.z + v.w*v.w;   // exact kde_pre order
            w[2*kk+0] = pack2_scaled(v.x, v.y);
            w[2*kk+1] = pack2_scaled(v.z, v.w);
        }
        uint4* bl = (uint4*)(smem + row * 32);
        bl[0] = make_uint4(w[0], w[1], w[2], w[3]);
        bl[1] = make_uint4(w[4], w[5], w[6], w[7]);
        *(float*)(smem + 32768 + row * 4) = THR + C72 * q;   // thr = THR - pb
    }

    // ---- A fragment + pe, converted in-wave from raw fp32 ----
    const int col  = lane & 31;   // A row / B col / C col
    const int half = lane >> 5;   // k-half for A/B frags; row-group for C

    {
        const float4* a4 = (const float4*)(xe + (size_t)(m0 + col) * KDE_D);
        float4 v0 = a4[0], v1 = a4[1], v2 = a4[2], v3 = a4[3];
        float q = 0.f;
        q += v0.x*v0.x + v0.y*v0.y + v0.z*v0.z + v0.w*v0.w;  // exact kde_pre order
        q += v1.x*v1.x + v1.y*v1.y + v1.z*v1.z + v1.w*v1.w;
        q += v2.x*v2.x + v2.y*v2.y + v2.z*v2.z + v2.w*v2.w;
        q += v3.x*v3.x + v3.y*v3.y + v3.z*v3.z + v3.w*v3.w;
        const float pev = T1L2E - C72 * q;
        if (lane < 32)
            *(float*)(smem + 36864 + (wave * 32 + col) * 4) = pev;

        const float4 va = half ? v2 : v0;
        const float4 vb = half ? v3 : v1;
        union { unsigned int u[4]; short8 s; } afu;
        afu.u[0] = pack2_scaled(va.x, va.y);
        afu.u[1] = pack2_scaled(va.z, va.w);
        afu.u[2] = pack2_scaled(vb.x, vb.y);
        afu.u[3] = pack2_scaled(vb.z, vb.w);

        __syncthreads();   // B slice + thr + pe exchange all resident

        // C operand = pe for the 16 C rows this lane owns:
        // row(r) = (r&3) + 8*(r>>2) + 4*half  -> quads at +0/+8/+16/+24
        const float4* pq = (const float4*)(smem + 36864 + (wave * 32 + 4 * half) * 4);
        const float4 q0 = pq[0], q1 = pq[2], q2 = pq[4], q3 = pq[6];
        float16_t perv;
        perv[0]=q0.x;  perv[1]=q0.y;  perv[2]=q0.z;  perv[3]=q0.w;
        perv[4]=q1.x;  perv[5]=q1.y;  perv[6]=q1.z;  perv[7]=q1.w;
        perv[8]=q2.x;  perv[9]=q2.y;  perv[10]=q2.z; perv[11]=q2.w;
        perv[12]=q3.x; perv[13]=q3.y; perv[14]=q3.z; perv[15]=q3.w;

        const short8 af = afu.s;
        const float INVN = 1.0f / (float)KDE_N;

        auto screen = [&](const float16_t& d, float thrv) {
            // max over this lane's 16 values, max3-friendly shape
            float m1 = fmaxf(fmaxf(d[0],  d[1]),  d[2]);
            float m2 = fmaxf(fmaxf(d[3],  d[4]),  d[5]);
            float m3 = fmaxf(fmaxf(d[6],  d[7]),  d[8]);
            float m4 = fmaxf(fmaxf(d[9],  d[10]), d[11]);
            float m5 = fmaxf(fmaxf(d[12], d[13]), d[14]);
            float x  = fmaxf(fmaxf(m1, m2), m3);
            float y  = fmaxf(fmaxf(m4, m5), d[15]);
            float mx = fmaxf(x, y);
            if (__any(mx > thrv)) {
                // rare: some term may exceed 2^-135
                const float pbv = THR - thrv;
                #pragma unroll
                for (int r = 0; r < 16; ++r) {
                    float e = exp2f(d[r] + pbv);
                    if (e != 0.f) {
                        const int row = m0 + (r & 3) + 8 * (r >> 2) + 4 * half;
                        float old  = atomicAdd(&S[row], e);
                        float cand = logf(1e-8f + (old + e) * INVN);
                        // all cands negative: float-max == uint-min on raw bits
                        atomicMin((unsigned int*)&out[row], __float_as_uint(cand));
                    }
                }
            }
        };

        // ---- flat loop: every LDS read is base + compile-time immediate ----
        const char* bbase = smem + col * 32 + half * 16;
        const char* tbase = smem + 32768 + col * 4;
        #pragma unroll 8
        for (int t = 0; t < JTILES; ++t) {
            const short8 bf   = *(const short8*)(bbase + t * 1024);
            const float  thrv = *(const float*)(tbase + t * 128);
            float16_t d = __builtin_amdgcn_mfma_f32_32x32x16_bf16(af, bf, perv, 0, 0, 0);
            screen(d, thrv);
        }
    }
}

extern "C" void kernel_launch(void* const* d_in, const int* in_sizes, int n_in,
                              void* d_out, int out_size, void* d_ws, size_t ws_size,
                              hipStream_t stream)
{
    const float* xe = (const float*)d_in[0];  // x_eval [16384,16] fp32
    const float* xb = (const float*)d_in[1];  // x_base [16384,16] fp32
    float* out = (float*)d_out;

    // ws layout: S[16384] only
    float* S = (float*)d_ws;

    kde_init<<<KDE_N / (256 * 4), 256, 0, stream>>>(S, out);   // 16 blocks
    dim3 grid(JSPLIT, KDE_N / MB);   // (16, 64) = 1024 blocks = 4/CU, resident
    kde_main<<<grid, MWAVES * 64, 0, stream>>>(xe, xb, S, out);
}